// Round 18
// baseline (42.027 us; speedup 1.0000x reference)
//
#include <hip/hip_runtime.h>
#include <hip/hip_bf16.h>

typedef __attribute__((ext_vector_type(8))) short s16x8;
typedef __attribute__((ext_vector_type(4))) short s16x4;
typedef __attribute__((ext_vector_type(4))) float fx4;

#define DEVINL __device__ __forceinline__

constexpr int EMBED = 768;
constexpr int HD    = 64;
constexpr int NB    = 16;
constexpr int LEN   = 1024;
constexpr int M_TOT = NB * LEN;   // 16384
constexpr int KVQ   = LEN / 4;    // 256 kv per group in fused attn
constexpr int WELEM = HD * EMBED; // 49152

// fp32 -> bf16 RNE via v_cvt_pk_bf16_f32 (2 elems/inst).
DEVINL unsigned pk2(float lo, float hi) {
  __hip_bfloat162 h = __float22bfloat162_rn(float2{lo, hi});
  union { __hip_bfloat162 h; unsigned u; } c; c.h = h;
  return c.u;
}
DEVINL s16x8 cvt8(fx4 a, fx4 b) {
  union { unsigned u[4]; s16x8 v; } r;
  r.u[0] = pk2(a[0], a[1]); r.u[1] = pk2(a[2], a[3]);
  r.u[2] = pk2(b[0], b[1]); r.u[3] = pk2(b[2], b[3]);
  return r.v;
}
DEVINL s16x4 cvt4(float a0, float a1, float a2, float a3) {
  union { unsigned u[2]; s16x4 v; } r;
  r.u[0] = pk2(a0, a1); r.u[1] = pk2(a2, a3);
  return r.v;
}

DEVINL fx4 mfma16(s16x8 a, s16x8 b, fx4 c) {
  return __builtin_amdgcn_mfma_f32_16x16x32_bf16(a, b, c, 0, 0, 0);
}

// async global->LDS DMA, 16B/lane; LDS dest = wave-uniform base + lane*16,
// global source = per-lane (enables source-side swizzle, m173 pattern).
DEVINL void gload16(const void* g, void* l) {
  __builtin_amdgcn_global_load_lds(
      (const __attribute__((address_space(1))) void*)g,
      (__attribute__((address_space(3))) void*)l, 16, 0, 0);
}

// ---------------------------------------------------------------------------
// One-shot: convert Wq|Wk|Wv (each 64x768 fp32) to bf16, packed [3][49152].
// ---------------------------------------------------------------------------
__global__ __launch_bounds__(256) void convert_w_kernel(
    const float* __restrict__ a, const float* __restrict__ b,
    const float* __restrict__ c, short* __restrict__ out)
{
  const int gid = blockIdx.x * 256 + threadIdx.x;   // 18432 threads, 8 elem each
  const int seg = gid / (WELEM / 8);
  const int off = (gid % (WELEM / 8)) * 8;
  const float* src = (seg == 0) ? a : (seg == 1) ? b : c;
  fx4 v0 = *reinterpret_cast<const fx4*>(src + off);
  fx4 v1 = *reinterpret_cast<const fx4*>(src + off + 4);
  *reinterpret_cast<s16x8*>(out + (size_t)seg * WELEM + off) = cvt8(v0, v1);
}

// ---------------------------------------------------------------------------
// Round-18 projection: minimum staged-bytes at the best measured staging
// configuration. Within-run evidence (r12 warm rocprof): 16-wave plain-
// __syncthreads staging sustains ~5.9 TB/s from L2/L3; my counted-vmcnt
// variants (r13/r15) only ~3.9 -> keep the compiler's own drain schedule.
// Bytes: BM=128 amortizes W over 2x rows vs r17 -> staged 132 MB total
// (X 96 unique + W 36 re-staged).
//   grid 256 x 1024 thr: blocks [0,128) Q from dec, [128,256) K+V^T enc.
//   BK=64 -> 12 steps. Per wave per step: 2 X gload16 + (<=1) W gload16.
//   LDS: dbuf x (X 32KB + W1 8KB + W2 8KB) = 96 KB -> 1 block/CU, 16 waves.
//   Compute: wave (mg=w>>1, nh=w&1): Q 4 MFMA/step, KV 8.
//   Source-XOR swizzles (r16/r17-verified family): X 256B-pitch rows key
//   (row&7)<<4; W 128B-pitch rows key (row&7)<<4; undone at read.
// ---------------------------------------------------------------------------
template <bool ISQ>
DEVINL void proj_body(const float* __restrict__ X,
                      const short* __restrict__ W1, const short* __restrict__ W2,
                      const float* __restrict__ b1, const float* __restrict__ b2,
                      short* __restrict__ O1, short* __restrict__ VT,
                      int m0, char* smem)
{
  constexpr int NST   = 12;
  constexpr int BUFSZ = 49152;   // X 32768 @0, W1 8192 @32768, W2 8192 @40960
  const int t = threadIdx.x, lane = t & 63, w = t >> 6;   // w = 0..15
  const int fr = lane & 15, fg = lane >> 4;
  const char* Xg = (const char*)(X + (size_t)m0 * EMBED);

  // X staging: all 16 waves, 2 instr each (32 KB/step)
  const int p0 = w * 2048 + lane * 16, p1 = p0 + 1024;
  const int xr0 = p0 >> 8, xc0 = p0 & 255;
  const int xr1 = p1 >> 8, xc1 = p1 & 255;
  const int xs0 = xr0 * 3072 + (xc0 ^ ((xr0 & 7) << 4));
  const int xs1 = xr1 * 3072 + (xc1 ^ ((xr1 & 7) << 4));
  // W staging: waves 0-7 -> W1; waves 8-15 -> W2 (KV only); 1 instr each
  const int wq  = (w & 7) * 1024 + lane * 16;
  const int wrr = wq >> 7, wcc = wq & 127;
  const int wsrc = wrr * 1536 + (wcc ^ ((wrr & 7) << 4));
  const bool doW = ISQ ? (w < 8) : true;
  const char* Wg = (const char*)((w < 8) ? W1 : W2);
  const int wdst = ((w < 8) ? 32768 : 40960) + wq;

  auto stage = [&](int k) {
    char* buf = smem + (k & 1) * BUFSZ;
    gload16(Xg + k * 256 + xs0, buf + p0);
    gload16(Xg + k * 256 + xs1, buf + p1);
    if (doW) gload16(Wg + k * 128 + wsrc, buf + wdst);
  };

  const int mg = w >> 1, nh = w & 1;
  fx4 a1[2], a2[2];
#pragma unroll
  for (int i = 0; i < 2; ++i) {
    a1[i] = fx4{0.f, 0.f, 0.f, 0.f};
    a2[i] = fx4{0.f, 0.f, 0.f, 0.f};
  }
  const int xrow = mg * 16 + fr;
  const int xsw  = (xrow & 7) << 4;

  auto compute = [&](int k) {
    const char* cur = smem + (k & 1) * BUFSZ;
    const char* xrb = cur + xrow * 256;
#pragma unroll
    for (int ks = 0; ks < 2; ++ks) {
      fx4 xlo = *reinterpret_cast<const fx4*>(xrb + ((ks * 128 + fg * 32) ^ xsw));
      fx4 xhi = *reinterpret_cast<const fx4*>(xrb + ((ks * 128 + fg * 32 + 16) ^ xsw));
      s16x8 xa = cvt8(xlo, xhi);
#pragma unroll
      for (int nt = 0; nt < 2; ++nt) {
        const int wr = nh * 32 + nt * 16 + fr;
        const int wo = wr * 128 + ((ks * 64 + fg * 16) ^ ((wr & 7) << 4));
        s16x8 wf1 = *reinterpret_cast<const s16x8*>(cur + 32768 + wo);
        a1[nt] = mfma16(wf1, xa, a1[nt]);
        if (!ISQ) {
          s16x8 wf2 = *reinterpret_cast<const s16x8*>(cur + 40960 + wo);
          a2[nt] = mfma16(wf2, xa, a2[nt]);
        }
      }
    }
  };

  stage(0);
  __syncthreads();
#pragma unroll 2
  for (int k = 0; k < NST; ++k) {
    if (k + 1 < NST) stage(k + 1);
    compute(k);
    __syncthreads();
  }

  // epilogue: D[n][m]: n = nh*32 + nt*16 + fg*4 + r; m = m0 + mg*16 + fr
  const int m = m0 + mg * 16 + fr;
#pragma unroll
  for (int nt = 0; nt < 2; ++nt) {
    const int n0 = nh * 32 + nt * 16 + fg * 4;
    fx4 b14 = *reinterpret_cast<const fx4*>(b1 + n0);
    *reinterpret_cast<s16x4*>(O1 + (size_t)m * HD + n0) =
        cvt4(a1[nt][0] + b14[0], a1[nt][1] + b14[1],
             a1[nt][2] + b14[2], a1[nt][3] + b14[3]);
    if (!ISQ) {
      fx4 b24 = *reinterpret_cast<const fx4*>(b2 + n0);
      const int bidx = m0 >> 10;             // 128 | 1024: no batch straddle
      const int kvp  = (m0 & 1023) + mg * 16 + fr;
#pragma unroll
      for (int r = 0; r < 4; ++r)
        VT[((size_t)(bidx * HD + n0 + r)) * LEN + kvp] =
            (short)pk2(a2[nt][r] + b24[r], 0.f);
    }
  }
}

__global__ __launch_bounds__(1024, 1) void proj_kernel(
    const float* __restrict__ dec, const float* __restrict__ enc,
    const short* __restrict__ wbuf,   // [3][WELEM] bf16: Wq | Wk | Wv
    const float* __restrict__ bq, const float* __restrict__ bk,
    const float* __restrict__ bv,
    short* __restrict__ Qout, short* __restrict__ Kout,
    short* __restrict__ VT)
{
  __shared__ __align__(16) char smem[98304];
  if (blockIdx.x < 128) {
    proj_body<true>(dec, wbuf, nullptr, bq, nullptr,
                    Qout, nullptr, (int)blockIdx.x * 128, smem);
  } else {
    proj_body<false>(enc, wbuf + WELEM, wbuf + 2 * (size_t)WELEM, bk, bv,
                     Kout, VT, ((int)blockIdx.x - 128) * 128, smem);
  }
}

// ---------------------------------------------------------------------------
// Fused flash attention (unchanged; proven r5-r17 form).
// 1024 threads = 16 waves = 4 KV-groups x 4 q-waves; K/V LDS-staged per
// group; lane-local softmax; partial combine through LDS overlay.
// ---------------------------------------------------------------------------
__global__ __launch_bounds__(1024, 4) void attn_kernel(
    const short* __restrict__ Q, const short* __restrict__ K,
    const short* __restrict__ VT, float* __restrict__ Out)
{
  __shared__ __align__(16) char smem[110592];
  short (*Kls)[64][72]  = reinterpret_cast<short(*)[64][72]>(smem);
  short (*Vls)[64][72]  = reinterpret_cast<short(*)[64][72]>(smem + 36864);
  short (*Plds)[16][72] = reinterpret_cast<short(*)[16][72]>(smem + 73728);
  float (*HL)[64][68]   = reinterpret_cast<float(*)[64][68]>(smem);
  float2 (*ML)[64]      = reinterpret_cast<float2(*)[64]>(smem + 69632);

  const int t = threadIdx.x, lane = t & 63, w = t >> 6;
  const int g = w >> 2, wl = w & 3;
  const int fr = lane & 15, fg = lane >> 4;
  const int xcd = blockIdx.x & 7;
  const int idx = blockIdx.x >> 3;        // 0..31
  const int b   = xcd + ((idx & 1) << 3);
  const int q0  = (idx >> 1) * 64;
  const int qrow = q0 + wl * 16;

  const short* Qb  = Q  + (size_t)b * LEN * HD;
  const short* Kb  = K  + ((size_t)b * LEN + g * KVQ) * HD;
  const short* VTb = VT + (size_t)b * HD * LEN + g * KVQ;

  s16x8 qa0 = *reinterpret_cast<const s16x8*>(Qb + (size_t)(qrow + fr) * HD + fg * 8);
  s16x8 qa1 = *reinterpret_cast<const s16x8*>(Qb + (size_t)(qrow + fr) * HD + 32 + fg * 8);

  fx4 hacc[4];
#pragma unroll
  for (int c = 0; c < 4; ++c) hacc[c] = fx4{0.f, 0.f, 0.f, 0.f};
  float mrun = -1e30f, lsum = 0.f;
  const float SC = 0.125f * 1.44269504088896340736f;  // 1/sqrt(64) * log2(e)

  const int u = t & 255;
  const int srow = u >> 2;          // 0..63
  const int sch  = (u & 3) * 16;    // short col offset: 0,16,32,48 (32B/lane)

  s16x8 pk0 = *reinterpret_cast<const s16x8*>(Kb + (size_t)srow * HD + sch);
  s16x8 pk1 = *reinterpret_cast<const s16x8*>(Kb + (size_t)srow * HD + sch + 8);
  s16x8 pv0 = *reinterpret_cast<const s16x8*>(VTb + (size_t)srow * LEN + sch);
  s16x8 pv1 = *reinterpret_cast<const s16x8*>(VTb + (size_t)srow * LEN + sch + 8);
  *reinterpret_cast<s16x8*>(&Kls[g][srow][sch])     = pk0;
  *reinterpret_cast<s16x8*>(&Kls[g][srow][sch + 8]) = pk1;
  *reinterpret_cast<s16x8*>(&Vls[g][srow][sch])     = pv0;
  *reinterpret_cast<s16x8*>(&Vls[g][srow][sch + 8]) = pv1;
  __syncthreads();

#pragma unroll
  for (int it = 0; it < KVQ / 64; ++it) {
    if (it + 1 < KVQ / 64) {  // issue next tile's loads before compute
      const int nk = (it + 1) * 64;
      pk0 = *reinterpret_cast<const s16x8*>(Kb + (size_t)(nk + srow) * HD + sch);
      pk1 = *reinterpret_cast<const s16x8*>(Kb + (size_t)(nk + srow) * HD + sch + 8);
      pv0 = *reinterpret_cast<const s16x8*>(VTb + (size_t)srow * LEN + nk + sch);
      pv1 = *reinterpret_cast<const s16x8*>(VTb + (size_t)srow * LEN + nk + sch + 8);
    }
    fx4 sacc[4];
#pragma unroll
    for (int s = 0; s < 4; ++s) {
      s16x8 kf0 = *reinterpret_cast<const s16x8*>(&Kls[g][s * 16 + fr][fg * 8]);
      s16x8 kf1 = *reinterpret_cast<const s16x8*>(&Kls[g][s * 16 + fr][32 + fg * 8]);
      fx4 z = fx4{0.f, 0.f, 0.f, 0.f};
      z = mfma16(kf0, qa0, z);
      sacc[s] = mfma16(kf1, qa1, z);
    }
    float xs[4][4];
    float xm = -1e30f;
#pragma unroll
    for (int s = 0; s < 4; ++s)
#pragma unroll
      for (int r = 0; r < 4; ++r) {
        xs[s][r] = sacc[s][r] * SC;
        xm = fmaxf(xm, xs[s][r]);
      }
    xm = fmaxf(xm, __shfl_xor(xm, 16, 64));
    xm = fmaxf(xm, __shfl_xor(xm, 32, 64));
    const float mn = fmaxf(mrun, xm);
    const float corr = __builtin_amdgcn_exp2f(mrun - mn);
    mrun = mn;
    float ps = 0.f;
#pragma unroll
    for (int s = 0; s < 4; ++s) {
      float p[4];
#pragma unroll
      for (int r = 0; r < 4; ++r) {
        p[r] = __builtin_amdgcn_exp2f(xs[s][r] - mn);
        ps += p[r];
      }
      *reinterpret_cast<s16x4*>(&Plds[w][fr][s * 16 + fg * 4]) =
          cvt4(p[0], p[1], p[2], p[3]);
    }
    ps += __shfl_xor(ps, 16, 64);
    ps += __shfl_xor(ps, 32, 64);
    lsum = lsum * corr + ps;
    __builtin_amdgcn_wave_barrier();
    s16x8 pa0 = *reinterpret_cast<const s16x8*>(&Plds[w][fr][fg * 8]);
    s16x8 pa1 = *reinterpret_cast<const s16x8*>(&Plds[w][fr][32 + fg * 8]);
#pragma unroll
    for (int c = 0; c < 4; ++c) {
      s16x8 vf0 = *reinterpret_cast<const s16x8*>(&Vls[g][c * 16 + fr][fg * 8]);
      s16x8 vf1 = *reinterpret_cast<const s16x8*>(&Vls[g][c * 16 + fr][32 + fg * 8]);
      fx4 h = hacc[c];
#pragma unroll
      for (int r = 0; r < 4; ++r) h[r] *= corr;
      h = mfma16(vf0, pa0, h);
      hacc[c] = mfma16(vf1, pa1, h);
    }
    __syncthreads();  // all waves done reading tile it
    if (it + 1 < KVQ / 64) {
      *reinterpret_cast<s16x8*>(&Kls[g][srow][sch])     = pk0;
      *reinterpret_cast<s16x8*>(&Kls[g][srow][sch + 8]) = pk1;
      *reinterpret_cast<s16x8*>(&Vls[g][srow][sch])     = pv0;
      *reinterpret_cast<s16x8*>(&Vls[g][srow][sch + 8]) = pv1;
    }
    __syncthreads();  // tile it+1 visible
  }
#pragma unroll
  for (int c = 0; c < 4; ++c)
    *reinterpret_cast<fx4*>(&HL[g][wl * 16 + fr][c * 16 + fg * 4]) = hacc[c];
  if (fg == 0) ML[g][wl * 16 + fr] = make_float2(mrun, lsum);
  __syncthreads();
  const int row = t >> 4, d0 = (t & 15) * 4;
  const float2 s0 = ML[0][row], s1 = ML[1][row], s2 = ML[2][row], s3 = ML[3][row];
  const float mm = fmaxf(fmaxf(s0.x, s1.x), fmaxf(s2.x, s3.x));
  const float w0 = __builtin_amdgcn_exp2f(s0.x - mm);
  const float w1 = __builtin_amdgcn_exp2f(s1.x - mm);
  const float w2 = __builtin_amdgcn_exp2f(s2.x - mm);
  const float w3 = __builtin_amdgcn_exp2f(s3.x - mm);
  const float inv = 1.0f / (s0.y * w0 + s1.y * w1 + s2.y * w2 + s3.y * w3);
  fx4 h0 = *reinterpret_cast<const fx4*>(&HL[0][row][d0]);
  fx4 h1 = *reinterpret_cast<const fx4*>(&HL[1][row][d0]);
  fx4 h2 = *reinterpret_cast<const fx4*>(&HL[2][row][d0]);
  fx4 h3 = *reinterpret_cast<const fx4*>(&HL[3][row][d0]);
  fx4 o;
#pragma unroll
  for (int r = 0; r < 4; ++r)
    o[r] = (h0[r] * w0 + h1[r] * w1 + h2[r] * w2 + h3[r] * w3) * inv;
  *reinterpret_cast<fx4*>(Out + ((size_t)b * LEN + q0 + row) * HD + d0) = o;
}

extern "C" void kernel_launch(void* const* d_in, const int* in_sizes, int n_in,
                              void* d_out, int out_size, void* d_ws, size_t ws_size,
                              hipStream_t stream) {
  const float* dec = (const float*)d_in[0];
  const float* enc = (const float*)d_in[1];
  const float* Wq  = (const float*)d_in[2];
  const float* bq  = (const float*)d_in[3];
  const float* Wk  = (const float*)d_in[4];
  const float* bk  = (const float*)d_in[5];
  const float* Wv  = (const float*)d_in[6];
  const float* bv  = (const float*)d_in[7];
  float* out = (float*)d_out;

  short* qws  = (short*)d_ws;                        // [16384,64] bf16
  short* kws  = qws + (size_t)M_TOT * HD;            // [16384,64] bf16
  short* vtws = kws + (size_t)M_TOT * HD;            // [16,64,1024] bf16
  short* wbuf = vtws + (size_t)NB * HD * LEN;        // [3][49152] bf16 weights

  convert_w_kernel<<<(3 * WELEM / 8) / 256, 256, 0, stream>>>(Wq, Wk, Wv, wbuf);
  proj_kernel<<<256, 1024, 0, stream>>>(
      dec, enc, wbuf, bq, bk, bv, qws, kws, vtws);
  attn_kernel<<<NB * (LEN / 64), 1024, 0, stream>>>(qws, kws, vtws, out);
}

// Round 19
// 39.941 us; speedup vs baseline: 1.0522x; 1.0522x over previous
//
#include <hip/hip_runtime.h>
#include <hip/hip_bf16.h>

typedef __attribute__((ext_vector_type(8))) short s16x8;
typedef __attribute__((ext_vector_type(4))) short s16x4;
typedef __attribute__((ext_vector_type(4))) float fx4;

#define DEVINL __device__ __forceinline__

constexpr int EMBED = 768;
constexpr int HD    = 64;
constexpr int NB    = 16;
constexpr int LEN   = 1024;
constexpr int M_TOT = NB * LEN;   // 16384
constexpr int KVQ   = LEN / 4;    // 256 kv per group in fused attn
constexpr int WELEM = HD * EMBED; // 49152
constexpr int BM    = 64;
constexpr int NSTEP = EMBED / 32; // 24

// fp32 -> bf16 RNE via v_cvt_pk_bf16_f32 (2 elems/inst).
DEVINL unsigned pk2(float lo, float hi) {
  __hip_bfloat162 h = __float22bfloat162_rn(float2{lo, hi});
  union { __hip_bfloat162 h; unsigned u; } c; c.h = h;
  return c.u;
}
DEVINL s16x8 cvt8(fx4 a, fx4 b) {
  union { unsigned u[4]; s16x8 v; } r;
  r.u[0] = pk2(a[0], a[1]); r.u[1] = pk2(a[2], a[3]);
  r.u[2] = pk2(b[0], b[1]); r.u[3] = pk2(b[2], b[3]);
  return r.v;
}
DEVINL s16x4 cvt4(float a0, float a1, float a2, float a3) {
  union { unsigned u[2]; s16x4 v; } r;
  r.u[0] = pk2(a0, a1); r.u[1] = pk2(a2, a3);
  return r.v;
}

DEVINL fx4 mfma16(s16x8 a, s16x8 b, fx4 c) {
  return __builtin_amdgcn_mfma_f32_16x16x32_bf16(a, b, c, 0, 0, 0);
}

// async global->LDS DMA, 16B/lane; LDS dest = wave-uniform base + lane*16,
// global source = per-lane (enables source-side swizzle, m173 pattern).
DEVINL void gload16(const void* g, void* l) {
  __builtin_amdgcn_global_load_lds(
      (const __attribute__((address_space(1))) void*)g,
      (__attribute__((address_space(3))) void*)l, 16, 0, 0);
}

// ---------------------------------------------------------------------------
// One-shot: convert Wq|Wk|Wv (each 64x768 fp32) to bf16, packed [3][49152].
// ---------------------------------------------------------------------------
__global__ __launch_bounds__(256) void convert_w_kernel(
    const float* __restrict__ a, const float* __restrict__ b,
    const float* __restrict__ c, short* __restrict__ out)
{
  const int gid = blockIdx.x * 256 + threadIdx.x;   // 18432 threads, 8 elem each
  const int seg = gid / (WELEM / 8);
  const int off = (gid % (WELEM / 8)) * 8;
  const float* src = (seg == 0) ? a : (seg == 1) ? b : c;
  fx4 v0 = *reinterpret_cast<const fx4*>(src + off);
  fx4 v1 = *reinterpret_cast<const fx4*>(src + off + 4);
  *reinterpret_cast<s16x8*>(out + (size_t)seg * WELEM + off) = cvt8(v0, v1);
}

// ---------------------------------------------------------------------------
// Projection (r11, the measured session best: 39.5 us total): m97-style
// STEP-LOOP pipeline. 512 blocks x 256 thr: [0,256) Q from dec, [256,512)
// K+V^T from enc. BM=64 rows/block, 24 K-steps of BK=32, double-buffered LDS.
// Per step: STAGE(next tile via global_load_lds) -> ds_read+MFMA(current)
// -> __syncthreads. Loads re-issued EVERY step so the CU memory queue never
// drains (single-burst designs idled it ~80%).
//   X staged fp32 (8KB/step), source-XOR swizzle (row&7)<<4 -> 2-way on read.
//   W staged bf16 (4KB/step each), swizzle (row&3)<<4.
//   Each wave: 16 m-rows, full N=64, full K accumulate -> no reduce phase.
// r12-r18 explored BM in {32,128}, 8/16-wave blocks, counted-vmcnt, byte
// minimization: all tied or regressed (40.2-42.0) -> this is the optimum
// reachable under the observed ~40 us plateau.
// ---------------------------------------------------------------------------
__global__ __launch_bounds__(256, 4) void proj_kernel(
    const float* __restrict__ dec, const float* __restrict__ enc,
    const short* __restrict__ wbuf,   // [3][WELEM] bf16: Wq | Wk | Wv
    const float* __restrict__ bq, const float* __restrict__ bk,
    const float* __restrict__ bv,
    short* __restrict__ Qout, short* __restrict__ Kout,
    short* __restrict__ VT)
{
  // buffer b at smem + b*16384:
  //   X  [64 rows][128 B] @ 0     (8 KB, fp32, swizzled)
  //   W1 [64 rows][64 B]  @ 8192  (4 KB, bf16, swizzled)
  //   W2 [64 rows][64 B]  @ 12288 (4 KB, bf16, KV only)
  __shared__ __align__(16) char smem[32768];

  const int t = threadIdx.x, lane = t & 63, w = t >> 6;
  const int fr = lane & 15, fg = lane >> 4;
  const bool isQ = blockIdx.x < 256u;
  const int bx = isQ ? blockIdx.x : blockIdx.x - 256;
  const int m0 = bx * BM;
  const float* X = isQ ? dec : enc;
  const char* Xg  = (const char*)(X + (size_t)m0 * EMBED);
  const char* W1g = (const char*)(isQ ? wbuf : wbuf + WELEM);
  const char* W2g = (const char*)(wbuf + 2 * (size_t)WELEM);

  // per-lane source-address components (constant over steps)
  const int xp   = w * 2048 + lane * 16;          // covers 2 gload instrs
  const int xrow0 = xp >> 7;                      // row of 1st instr's lane
  const int xrow1 = (xp + 1024) >> 7;
  const int xcol0 = xp & 127, xcol1 = (xp + 1024) & 127;
  const int xsrc0 = xrow0 * 3072 + (xcol0 ^ ((xrow0 & 7) << 4));
  const int xsrc1 = xrow1 * 3072 + (xcol1 ^ ((xrow1 & 7) << 4));
  const int wp   = w * 1024 + lane * 16;
  const int wrow = wp >> 6, wcol = wp & 63;
  const int wsrc = wrow * 1536 + (wcol ^ ((wrow & 3) << 4));

  fx4 acc1[4], acc2[4];
#pragma unroll
  for (int j = 0; j < 4; ++j) {
    acc1[j] = fx4{0.f, 0.f, 0.f, 0.f};
    acc2[j] = fx4{0.f, 0.f, 0.f, 0.f};
  }

  // fragment-read constants
  const int xr = w * 16 + fr;                     // this lane's m-row in tile
  const int xsw = (xr & 7) << 4;

  // prologue: stage step 0
  {
    char* b0 = smem;
    gload16(Xg + xsrc0, b0 + w * 2048);
    gload16(Xg + xsrc1 + 0, b0 + w * 2048 + 1024);
    gload16(W1g + wsrc, b0 + 8192 + w * 1024);
    if (!isQ) gload16(W2g + wsrc, b0 + 12288 + w * 1024);
  }
  __syncthreads();

#pragma unroll 2
  for (int k = 0; k < NSTEP; ++k) {
    char* cur = smem + (k & 1) * 16384;
    // ---- stage next step into the other buffer (read-done via last barrier)
    if (k + 1 < NSTEP) {
      char* nxt = smem + ((k + 1) & 1) * 16384;
      const int ko = (k + 1) * 128;               // X byte col offset
      const int kw = (k + 1) * 64;                // W byte col offset
      gload16(Xg + ko + xsrc0, nxt + w * 2048);
      gload16(Xg + ko + xsrc1, nxt + w * 2048 + 1024);
      gload16(W1g + kw + wsrc, nxt + 8192 + w * 1024);
      if (!isQ) gload16(W2g + kw + wsrc, nxt + 12288 + w * 1024);
    }
    // ---- compute current step ----
    const char* xrb = cur + xr * 128;
    fx4 xlo = *reinterpret_cast<const fx4*>(xrb + ((fg * 32) ^ xsw));
    fx4 xhi = *reinterpret_cast<const fx4*>(xrb + ((fg * 32 + 16) ^ xsw));
    s16x8 xa = cvt8(xlo, xhi);
#pragma unroll
    for (int j = 0; j < 4; ++j) {
      const int wr = j * 16 + fr;
      const int wo = wr * 64 + ((fg * 16) ^ ((wr & 3) << 4));
      s16x8 wf1 = *reinterpret_cast<const s16x8*>(cur + 8192 + wo);
      acc1[j] = mfma16(wf1, xa, acc1[j]);
      if (!isQ) {
        s16x8 wf2 = *reinterpret_cast<const s16x8*>(cur + 12288 + wo);
        acc2[j] = mfma16(wf2, xa, acc2[j]);
      }
    }
    __syncthreads();   // waves done with cur; next-tile loads drained
  }

  // ---- epilogue: D[n][m]: n = j*16+fg*4+r, m-col = fr -> m = m0+w*16+fr ----
  const int m = m0 + w * 16 + fr;
  if (isQ) {
#pragma unroll
    for (int j = 0; j < 4; ++j) {
      fx4 bb = *reinterpret_cast<const fx4*>(bq + j * 16 + fg * 4);
      *reinterpret_cast<s16x4*>(Qout + (size_t)m * HD + j * 16 + fg * 4) =
          cvt4(acc1[j][0] + bb[0], acc1[j][1] + bb[1],
               acc1[j][2] + bb[2], acc1[j][3] + bb[3]);
    }
  } else {
#pragma unroll
    for (int j = 0; j < 4; ++j) {
      fx4 bb = *reinterpret_cast<const fx4*>(bk + j * 16 + fg * 4);
      *reinterpret_cast<s16x4*>(Kout + (size_t)m * HD + j * 16 + fg * 4) =
          cvt4(acc1[j][0] + bb[0], acc1[j][1] + bb[1],
               acc1[j][2] + bb[2], acc1[j][3] + bb[3]);
    }
    const int bidx = m0 >> 10;                    // 64 | 1024: no straddle
    const int kvp  = (m0 & 1023) + w * 16 + fr;
#pragma unroll
    for (int j = 0; j < 4; ++j) {
      fx4 bb = *reinterpret_cast<const fx4*>(bv + j * 16 + fg * 4);
#pragma unroll
      for (int r = 0; r < 4; ++r) {
        const int d = j * 16 + fg * 4 + r;
        VT[((size_t)(bidx * HD + d)) * LEN + kvp] =
            (short)pk2(acc2[j][r] + bb[r], 0.f);
      }
    }
  }
}

// ---------------------------------------------------------------------------
// Fused flash attention (proven r5-r18 form). 1024 threads = 16 waves =
// 4 KV-groups x 4 q-waves; K/V LDS-staged per group; lane-local softmax;
// partial combine through LDS overlay.
// ---------------------------------------------------------------------------
__global__ __launch_bounds__(1024, 4) void attn_kernel(
    const short* __restrict__ Q, const short* __restrict__ K,
    const short* __restrict__ VT, float* __restrict__ Out)
{
  __shared__ __align__(16) char smem[110592];
  short (*Kls)[64][72]  = reinterpret_cast<short(*)[64][72]>(smem);
  short (*Vls)[64][72]  = reinterpret_cast<short(*)[64][72]>(smem + 36864);
  short (*Plds)[16][72] = reinterpret_cast<short(*)[16][72]>(smem + 73728);
  float (*HL)[64][68]   = reinterpret_cast<float(*)[64][68]>(smem);
  float2 (*ML)[64]      = reinterpret_cast<float2(*)[64]>(smem + 69632);

  const int t = threadIdx.x, lane = t & 63, w = t >> 6;
  const int g = w >> 2, wl = w & 3;
  const int fr = lane & 15, fg = lane >> 4;
  const int xcd = blockIdx.x & 7;
  const int idx = blockIdx.x >> 3;        // 0..31
  const int b   = xcd + ((idx & 1) << 3);
  const int q0  = (idx >> 1) * 64;
  const int qrow = q0 + wl * 16;

  const short* Qb  = Q  + (size_t)b * LEN * HD;
  const short* Kb  = K  + ((size_t)b * LEN + g * KVQ) * HD;
  const short* VTb = VT + (size_t)b * HD * LEN + g * KVQ;

  s16x8 qa0 = *reinterpret_cast<const s16x8*>(Qb + (size_t)(qrow + fr) * HD + fg * 8);
  s16x8 qa1 = *reinterpret_cast<const s16x8*>(Qb + (size_t)(qrow + fr) * HD + 32 + fg * 8);

  fx4 hacc[4];
#pragma unroll
  for (int c = 0; c < 4; ++c) hacc[c] = fx4{0.f, 0.f, 0.f, 0.f};
  float mrun = -1e30f, lsum = 0.f;
  const float SC = 0.125f * 1.44269504088896340736f;  // 1/sqrt(64) * log2(e)

  const int u = t & 255;
  const int srow = u >> 2;          // 0..63
  const int sch  = (u & 3) * 16;    // short col offset: 0,16,32,48 (32B/lane)

  s16x8 pk0 = *reinterpret_cast<const s16x8*>(Kb + (size_t)srow * HD + sch);
  s16x8 pk1 = *reinterpret_cast<const s16x8*>(Kb + (size_t)srow * HD + sch + 8);
  s16x8 pv0 = *reinterpret_cast<const s16x8*>(VTb + (size_t)srow * LEN + sch);
  s16x8 pv1 = *reinterpret_cast<const s16x8*>(VTb + (size_t)srow * LEN + sch + 8);
  *reinterpret_cast<s16x8*>(&Kls[g][srow][sch])     = pk0;
  *reinterpret_cast<s16x8*>(&Kls[g][srow][sch + 8]) = pk1;
  *reinterpret_cast<s16x8*>(&Vls[g][srow][sch])     = pv0;
  *reinterpret_cast<s16x8*>(&Vls[g][srow][sch + 8]) = pv1;
  __syncthreads();

#pragma unroll
  for (int it = 0; it < KVQ / 64; ++it) {
    if (it + 1 < KVQ / 64) {  // issue next tile's loads before compute
      const int nk = (it + 1) * 64;
      pk0 = *reinterpret_cast<const s16x8*>(Kb + (size_t)(nk + srow) * HD + sch);
      pk1 = *reinterpret_cast<const s16x8*>(Kb + (size_t)(nk + srow) * HD + sch + 8);
      pv0 = *reinterpret_cast<const s16x8*>(VTb + (size_t)srow * LEN + nk + sch);
      pv1 = *reinterpret_cast<const s16x8*>(VTb + (size_t)srow * LEN + nk + sch + 8);
    }
    fx4 sacc[4];
#pragma unroll
    for (int s = 0; s < 4; ++s) {
      s16x8 kf0 = *reinterpret_cast<const s16x8*>(&Kls[g][s * 16 + fr][fg * 8]);
      s16x8 kf1 = *reinterpret_cast<const s16x8*>(&Kls[g][s * 16 + fr][32 + fg * 8]);
      fx4 z = fx4{0.f, 0.f, 0.f, 0.f};
      z = mfma16(kf0, qa0, z);
      sacc[s] = mfma16(kf1, qa1, z);
    }
    float xs[4][4];
    float xm = -1e30f;
#pragma unroll
    for (int s = 0; s < 4; ++s)
#pragma unroll
      for (int r = 0; r < 4; ++r) {
        xs[s][r] = sacc[s][r] * SC;
        xm = fmaxf(xm, xs[s][r]);
      }
    xm = fmaxf(xm, __shfl_xor(xm, 16, 64));
    xm = fmaxf(xm, __shfl_xor(xm, 32, 64));
    const float mn = fmaxf(mrun, xm);
    const float corr = __builtin_amdgcn_exp2f(mrun - mn);
    mrun = mn;
    float ps = 0.f;
#pragma unroll
    for (int s = 0; s < 4; ++s) {
      float p[4];
#pragma unroll
      for (int r = 0; r < 4; ++r) {
        p[r] = __builtin_amdgcn_exp2f(xs[s][r] - mn);
        ps += p[r];
      }
      *reinterpret_cast<s16x4*>(&Plds[w][fr][s * 16 + fg * 4]) =
          cvt4(p[0], p[1], p[2], p[3]);
    }
    ps += __shfl_xor(ps, 16, 64);
    ps += __shfl_xor(ps, 32, 64);
    lsum = lsum * corr + ps;
    __builtin_amdgcn_wave_barrier();
    s16x8 pa0 = *reinterpret_cast<const s16x8*>(&Plds[w][fr][fg * 8]);
    s16x8 pa1 = *reinterpret_cast<const s16x8*>(&Plds[w][fr][32 + fg * 8]);
#pragma unroll
    for (int c = 0; c < 4; ++c) {
      s16x8 vf0 = *reinterpret_cast<const s16x8*>(&Vls[g][c * 16 + fr][fg * 8]);
      s16x8 vf1 = *reinterpret_cast<const s16x8*>(&Vls[g][c * 16 + fr][32 + fg * 8]);
      fx4 h = hacc[c];
#pragma unroll
      for (int r = 0; r < 4; ++r) h[r] *= corr;
      h = mfma16(vf0, pa0, h);
      hacc[c] = mfma16(vf1, pa1, h);
    }
    __syncthreads();  // all waves done reading tile it
    if (it + 1 < KVQ / 64) {
      *reinterpret_cast<s16x8*>(&Kls[g][srow][sch])     = pk0;
      *reinterpret_cast<s16x8*>(&Kls[g][srow][sch + 8]) = pk1;
      *reinterpret_cast<s16x8*>(&Vls[g][srow][sch])     = pv0;
      *reinterpret_cast<s16x8*>(&Vls[g][srow][sch + 8]) = pv1;
    }
    __syncthreads();  // tile it+1 visible
  }
#pragma unroll
  for (int c = 0; c < 4; ++c)
    *reinterpret_cast<fx4*>(&HL[g][wl * 16 + fr][c * 16 + fg * 4]) = hacc[c];
  if (fg == 0) ML[g][wl * 16 + fr] = make_float2(mrun, lsum);
  __syncthreads();
  const int row = t >> 4, d0 = (t & 15) * 4;
  const float2 s0 = ML[0][row], s1 = ML[1][row], s2 = ML[2][row], s3 = ML[3][row];
  const float mm = fmaxf(fmaxf(s0.x, s1.x), fmaxf(s2.x, s3.x));
  const float w0 = __builtin_amdgcn_exp2f(s0.x - mm);
  const float w1 = __builtin_amdgcn_exp2f(s1.x - mm);
  const float w2 = __builtin_amdgcn_exp2f(s2.x - mm);
  const float w3 = __builtin_amdgcn_exp2f(s3.x - mm);
  const float inv = 1.0f / (s0.y * w0 + s1.y * w1 + s2.y * w2 + s3.y * w3);
  fx4 h0 = *reinterpret_cast<const fx4*>(&HL[0][row][d0]);
  fx4 h1 = *reinterpret_cast<const fx4*>(&HL[1][row][d0]);
  fx4 h2 = *reinterpret_cast<const fx4*>(&HL[2][row][d0]);
  fx4 h3 = *reinterpret_cast<const fx4*>(&HL[3][row][d0]);
  fx4 o;
#pragma unroll
  for (int r = 0; r < 4; ++r)
    o[r] = (h0[r] * w0 + h1[r] * w1 + h2[r] * w2 + h3[r] * w3) * inv;
  *reinterpret_cast<fx4*>(Out + ((size_t)b * LEN + q0 + row) * HD + d0) = o;
}

extern "C" void kernel_launch(void* const* d_in, const int* in_sizes, int n_in,
                              void* d_out, int out_size, void* d_ws, size_t ws_size,
                              hipStream_t stream) {
  const float* dec = (const float*)d_in[0];
  const float* enc = (const float*)d_in[1];
  const float* Wq  = (const float*)d_in[2];
  const float* bq  = (const float*)d_in[3];
  const float* Wk  = (const float*)d_in[4];
  const float* bk  = (const float*)d_in[5];
  const float* Wv  = (const float*)d_in[6];
  const float* bv  = (const float*)d_in[7];
  float* out = (float*)d_out;

  short* qws  = (short*)d_ws;                        // [16384,64] bf16
  short* kws  = qws + (size_t)M_TOT * HD;            // [16384,64] bf16
  short* vtws = kws + (size_t)M_TOT * HD;            // [16,64,1024] bf16
  short* wbuf = vtws + (size_t)NB * HD * LEN;        // [3][49152] bf16 weights

  convert_w_kernel<<<(3 * WELEM / 8) / 256, 256, 0, stream>>>(Wq, Wk, Wv, wbuf);
  proj_kernel<<<512, 256, 0, stream>>>(
      dec, enc, wbuf, bq, bk, bv, qws, kws, vtws);
  attn_kernel<<<NB * (LEN / 64), 1024, 0, stream>>>(qws, kws, vtws, out);
}